// Round 15
// baseline (993.795 us; speedup 1.0000x reference)
//
#include <hip/hip_runtime.h>
#include <stdint.h>
#include <stddef.h>

typedef float f32x16 __attribute__((ext_vector_type(16)));
typedef int i32x8 __attribute__((ext_vector_type(8)));

union Frag32 { long l[4]; i32x8 v; };  // 32 bytes = one scaled-MFMA operand/lane

// ---------------------------------------------------------------------------
// Image layout (A and B identical): per 256-row block, K/64 slices of 16 KB.
// Slice s covers k-bytes [s*64, s*64+64) of rows [blk*256, +256).
// Within a slice: rowgroup g = row>>5 owns a 2 KB sub-block at g*2048,
// ordered [c(16B half of kh)][kh(32B k-half)][row&31][16B]:
//   off(row, kb) = (row>>5)*2048 + ((kb>>4)&1)*1024 + (kb>>5)*512
//                  + (row&31)*16 + (kb&15)
// => a wave's fragment read (lane l: row g*32+(l&31), kh=l>>5) is
//    base + g*2048 + c*1024 + l*16  — lane-linear contiguous 1 KB:
//    canonical conflict-free ds_read_b128 (8 words/bank exactly).
// Fragment reads: 8 b128/wave/phase vs champion's 16 b64 — attacks the
// measured LDS-issue wall (2048 of 2686 cy/phase).
//
// GEMM: 256x256 tile, 16 waves of 64x64, mfma_scale 32x32x64 f8f6f4 with
// unit E8M0 scales (bit-exact fp8 at 2x MX rate), 4-slice LDS ring, lead-2
// linear gl_lds staging, counted vmcnt(2), one barrier/phase, 2D XCD chunk.
//
// Workspace: [0..7] amax slots | [256..) x_q 32MB | [+M*K..) w_qT 64MB.
// ---------------------------------------------------------------------------

__device__ __forceinline__ float max4(const float4 v) {
  return fmaxf(fmaxf(fabsf(v.x), fabsf(v.y)), fmaxf(fabsf(v.z), fabsf(v.w)));
}

// One kernel, both tensors: grid-stride scan of weight then inp, 4-way ILP.
__global__ void absmax_both_kernel(const float4* __restrict__ w, size_t wn4,
                                   const float4* __restrict__ x, size_t xn4,
                                   unsigned int* __restrict__ out) {
  const size_t tid0 = (size_t)blockIdx.x * blockDim.x + threadIdx.x;
  const size_t stride = (size_t)gridDim.x * blockDim.x * 4;
  float mw = 0.f, mx = 0.f;
  for (size_t i = tid0 * 4; i < wn4; i += stride) {
    float a = max4(w[i]), b = max4(w[i + 1]);
    float c = max4(w[i + 2]), d = max4(w[i + 3]);   // wn4 % 4 == 0
    mw = fmaxf(mw, fmaxf(fmaxf(a, b), fmaxf(c, d)));
  }
  for (size_t i = tid0 * 4; i < xn4; i += stride) {
    float a = max4(x[i]), b = max4(x[i + 1]);
    float c = max4(x[i + 2]), d = max4(x[i + 3]);   // xn4 % 4 == 0
    mx = fmaxf(mx, fmaxf(fmaxf(a, b), fmaxf(c, d)));
  }
#pragma unroll
  for (int off = 32; off > 0; off >>= 1) {
    mw = fmaxf(mw, __shfl_xor(mw, off));
    mx = fmaxf(mx, __shfl_xor(mx, off));
  }
  if ((threadIdx.x & 63) == 0) {
    atomicMax(out + 0, __float_as_uint(mw));  // vals >= 0: uint order == float
    atomicMax(out + 1, __float_as_uint(mx));
  }
}

// x [M][K] f32 -> slice image. One thread = one 16B output chunk (64B input,
// fully coalesced reads). ks16 = log2(K/16).
__global__ void quantize_x_kernel(const float4* __restrict__ x,
                                  uint8_t* __restrict__ xq,
                                  const unsigned int* __restrict__ amax,
                                  int K, int ks16, int n_chunks) {
  const float x_scale = __uint_as_float(amax[1]) / 448.0f;
  const float inv = 1.0f / x_scale;
  int idx = blockIdx.x * blockDim.x + threadIdx.x;
  const int stride = gridDim.x * blockDim.x;
  for (; idx < n_chunks; idx += stride) {
    const int row_g = idx >> ks16;
    const int kc16 = idx & ((1 << ks16) - 1);
    const int mblk = row_g >> 8;
    const int row = row_g & 255;
    const int s = kc16 >> 2;
    const int kh = (kc16 >> 1) & 1;
    const int c = kc16 & 1;
    const size_t f4 = (size_t)row_g * (K >> 2) + kc16 * 4;
    const float4 v0 = x[f4 + 0], v1 = x[f4 + 1], v2 = x[f4 + 2], v3 = x[f4 + 3];
    uint32_t c0 = __builtin_amdgcn_cvt_pk_fp8_f32(v0.x * inv, v0.y * inv, 0, false);
    c0 = __builtin_amdgcn_cvt_pk_fp8_f32(v0.z * inv, v0.w * inv, c0, true);
    uint32_t c1 = __builtin_amdgcn_cvt_pk_fp8_f32(v1.x * inv, v1.y * inv, 0, false);
    c1 = __builtin_amdgcn_cvt_pk_fp8_f32(v1.z * inv, v1.w * inv, c1, true);
    uint32_t c2 = __builtin_amdgcn_cvt_pk_fp8_f32(v2.x * inv, v2.y * inv, 0, false);
    c2 = __builtin_amdgcn_cvt_pk_fp8_f32(v2.z * inv, v2.w * inv, c2, true);
    uint32_t c3 = __builtin_amdgcn_cvt_pk_fp8_f32(v3.x * inv, v3.y * inv, 0, false);
    c3 = __builtin_amdgcn_cvt_pk_fp8_f32(v3.z * inv, v3.w * inv, c3, true);
    uint4 o;
    o.x = c0; o.y = c1; o.z = c2; o.w = c3;
    uint8_t* dst = xq + ((size_t)(mblk * (K >> 6) + s)) * 16384 +
                   (row >> 5) * 2048 + c * 1024 + kh * 512 + (row & 31) * 16;
    *(uint4*)dst = o;
  }
}

// w [K][N] f32 -> w^T slice image. 64n x 128k tile per block:
// f32 LDS tile [64][129] (conflict-free writes + b128 column reads),
// two 16B stores per thread (c=0 and c=1 sub-blocks).
__global__ void quantize_wT_kernel(const float* __restrict__ w,
                                   uint8_t* __restrict__ wqt,
                                   const unsigned int* __restrict__ amax,
                                   int N, int K) {
  __shared__ float tileF[64][129];
  const float w_scale = __uint_as_float(amax[0]) / 448.0f;
  const float inv = 1.0f / w_scale;
  const int tn = blockIdx.x;   // 64-wide n tile
  const int tk = blockIdx.y;   // 128-wide k tile
  const int t = threadIdx.x;
  {
    const int nn4 = t & 15;
    const int kk0 = t >> 4;    // 0..15
#pragma unroll
    for (int i = 0; i < 8; ++i) {
      const int kk = kk0 + i * 16;  // 0..127
      const float4 v =
          *(const float4*)&w[(size_t)(tk * 128 + kk) * N + tn * 64 + nn4 * 4];
      tileF[nn4 * 4 + 0][kk] = v.x;
      tileF[nn4 * 4 + 1][kk] = v.y;
      tileF[nn4 * 4 + 2][kk] = v.z;
      tileF[nn4 * 4 + 3][kk] = v.w;
    }
  }
  __syncthreads();
  {
    const int n = t & 63;
    const int ck = t >> 6;     // 0..3: which 32-k chunk (one kh of a slice)
    unsigned long long q[4];
#pragma unroll
    for (int cc = 0; cc < 4; ++cc) {
      const float4 u0 = *(const float4*)&tileF[n][ck * 32 + cc * 8];
      const float4 u1 = *(const float4*)&tileF[n][ck * 32 + cc * 8 + 4];
      uint32_t lo = __builtin_amdgcn_cvt_pk_fp8_f32(u0.x * inv, u0.y * inv, 0, false);
      lo = __builtin_amdgcn_cvt_pk_fp8_f32(u0.z * inv, u0.w * inv, lo, true);
      uint32_t hi = __builtin_amdgcn_cvt_pk_fp8_f32(u1.x * inv, u1.y * inv, 0, false);
      hi = __builtin_amdgcn_cvt_pk_fp8_f32(u1.z * inv, u1.w * inv, hi, true);
      q[cc] = (unsigned long long)lo | ((unsigned long long)hi << 32);
    }
    const int n_g = tn * 64 + n;
    const int k0g = tk * 128 + ck * 32;
    const int s = k0g >> 6;
    const int kh = (k0g >> 5) & 1;
    const int row = n_g & 255;
    uint8_t* base = wqt + ((size_t)((n_g >> 8) * (K >> 6) + s)) * 16384 +
                    (row >> 5) * 2048 + kh * 512 + (row & 31) * 16;
    ulonglong2 s0, s1;
    s0.x = q[0]; s0.y = q[1];   // k-bytes 0-15 of this kh -> c=0
    s1.x = q[2]; s1.y = q[3];   // k-bytes 16-31 -> c=1
    *(ulonglong2*)(base) = s0;
    *(ulonglong2*)(base + 1024) = s1;
  }
}

// ---------------------------------------------------------------------------
// fp8 GEMM: champion schedule, lane-linear b128 fragment reads.
// ---------------------------------------------------------------------------
#define T_BM 256
#define T_BN 256
#define UNIT_SCALE 0x7F7F7F7F

__device__ __forceinline__ void gl_lds16(const uint8_t* g, uint8_t* lds) {
  __builtin_amdgcn_global_load_lds(
      (const __attribute__((address_space(1))) void*)g,
      (__attribute__((address_space(3))) void*)lds, 16, 0, 0);
}

__global__ __launch_bounds__(1024, 4) void gemm_fp8_mx(
    const uint8_t* __restrict__ Aq, const uint8_t* __restrict__ BqT,
    const float* __restrict__ bias, const unsigned int* __restrict__ amax,
    float* __restrict__ C, int M, int N, int K) {
  extern __shared__ uint8_t smem[];
  uint8_t* const Ar = smem;            // 4 slices x 16384 = 64 KB
  uint8_t* const Br = smem + 65536;    // 4 slices x 16384 = 64 KB

  // 2D-chunked XCD swizzle: co-resident 32 blocks per XCD = 4(tm) x 8(tn).
  const int ntm = M / T_BM;            // 32
  const int mpx = ntm >> 3;            // 4 m-tiles per XCD
  const int bid = blockIdx.x;
  const int s = bid >> 3;
  const int tm = (bid & 7) * mpx + (s & (mpx - 1));
  const int tn = s / mpx;
  const int m0 = tm * T_BM;
  const int n0 = tn * T_BN;

  const int tid = threadIdx.x;
  const int w = tid >> 6;      // wave 0..15
  const int l = tid & 63;
  const int wr = w >> 2;       // 0..3  (M quarter)
  const int wc = w & 3;        // 0..3  (N quarter)

  const int kslices = K >> 6;

  // staging: linear contiguous copy of one 16 KB slice; wave w owns bytes
  // [w*1024, w*1024+1024), lane l the 16B at +l*16.
  const int soff = w * 1024 + l * 16;
  const uint8_t* a_src = Aq + (size_t)(m0 >> 8) * kslices * 16384 + soff;
  const uint8_t* b_src = BqT + (size_t)(n0 >> 8) * kslices * 16384 + soff;

  // fragment-read offsets: rowgroup g sub-block, lane-linear b128 reads.
  const int h = l >> 5;
  const int rl = l & 31;
  int aoff[2][2], boff[2][2];
#pragma unroll
  for (int mt = 0; mt < 2; ++mt) {
#pragma unroll
    for (int c = 0; c < 2; ++c) {
      aoff[mt][c] = (wr * 2 + mt) * 2048 + c * 1024 + l * 16;
      boff[mt][c] = (wc * 2 + mt) * 2048 + c * 1024 + l * 16;
    }
  }

  f32x16 acc[2][2];
#pragma unroll
  for (int i = 0; i < 2; ++i)
#pragma unroll
    for (int j = 0; j < 2; ++j) acc[i][j] = 0.f;

  const int NP = K >> 6;  // 64 phases (one 16 KB slice each)

  // prologue: stage slices 0,1 into ring slots 0,1
  gl_lds16(a_src, Ar + soff);
  gl_lds16(b_src, Br + soff);
  gl_lds16(a_src + 16384, Ar + 16384 + soff);
  gl_lds16(b_src + 16384, Br + 16384 + soff);
  asm volatile("s_waitcnt vmcnt(2)" ::: "memory");  // slice 0 landed
  __builtin_amdgcn_s_barrier();

  for (int p = 0; p < NP; ++p) {
    // 1. stage slice p+2 (tail: re-stage p-2 = same bytes into its dead slot)
    const int ss = (p + 2 < NP) ? (p + 2) : (p - 2);
    const int rslot = ((p + 2) & 3) * 16384;
    gl_lds16(a_src + (size_t)ss * 16384, Ar + rslot + soff);
    gl_lds16(b_src + (size_t)ss * 16384, Br + rslot + soff);

    // 2. fragments from ring slot p&3: lane-linear ds_read_b128
    const uint8_t* Asl = Ar + (p & 3) * 16384;
    const uint8_t* Bsl = Br + (p & 3) * 16384;
    Frag32 af[2], bf[2];
#pragma unroll
    for (int mt = 0; mt < 2; ++mt) {
      ulonglong2 a0 = *(const ulonglong2*)(Asl + aoff[mt][0]);
      ulonglong2 a1 = *(const ulonglong2*)(Asl + aoff[mt][1]);
      af[mt].l[0] = (long)a0.x; af[mt].l[1] = (long)a0.y;
      af[mt].l[2] = (long)a1.x; af[mt].l[3] = (long)a1.y;
      ulonglong2 b0 = *(const ulonglong2*)(Bsl + boff[mt][0]);
      ulonglong2 b1 = *(const ulonglong2*)(Bsl + boff[mt][1]);
      bf[mt].l[0] = (long)b0.x; bf[mt].l[1] = (long)b0.y;
      bf[mt].l[2] = (long)b1.x; bf[mt].l[3] = (long)b1.y;
    }

    // 3. 4 MFMAs (64x64 per wave)
    __builtin_amdgcn_s_setprio(1);
    acc[0][0] = __builtin_amdgcn_mfma_scale_f32_32x32x64_f8f6f4(
        af[0].v, bf[0].v, acc[0][0], 0, 0, 0, UNIT_SCALE, 0, UNIT_SCALE);
    acc[1][0] = __builtin_amdgcn_mfma_scale_f32_32x32x64_f8f6f4(
        af[1].v, bf[0].v, acc[1][0], 0, 0, 0, UNIT_SCALE, 0, UNIT_SCALE);
    acc[0][1] = __builtin_amdgcn_mfma_scale_f32_32x32x64_f8f6f4(
        af[0].v, bf[1].v, acc[0][1], 0, 0, 0, UNIT_SCALE, 0, UNIT_SCALE);
    acc[1][1] = __builtin_amdgcn_mfma_scale_f32_32x32x64_f8f6f4(
        af[1].v, bf[1].v, acc[1][1], 0, 0, 0, UNIT_SCALE, 0, UNIT_SCALE);
    __builtin_amdgcn_s_setprio(0);

    // 4. counted wait: slice p+1 must land; slice p+2's pair stays in flight
    asm volatile("s_waitcnt vmcnt(2)" ::: "memory");
    __builtin_amdgcn_s_barrier();
  }
  asm volatile("s_waitcnt vmcnt(0)" ::: "memory");  // drain tail dummies

  // epilogue: C = acc * (x_scale*w_scale) + bias
  // 32x32 C/D layout: col = l&31, row = (r&3) + 8*(r>>2) + 4*(l>>5)
  const float x_scale = __uint_as_float(amax[1]) / 448.0f;
  const float w_scale = __uint_as_float(amax[0]) / 448.0f;
  const float sc = x_scale * w_scale;
  const int colb = n0 + wc * 64 + rl;
  const int rowb = m0 + wr * 64 + 4 * h;
#pragma unroll
  for (int nt = 0; nt < 2; ++nt) {
    const int col = colb + nt * 32;
    const float bv = bias[col];
#pragma unroll
    for (int mt = 0; mt < 2; ++mt) {
#pragma unroll
      for (int r = 0; r < 16; ++r) {
        const int row = rowb + mt * 32 + (r & 3) + 8 * (r >> 2);
        C[(size_t)row * N + col] = acc[mt][nt][r] * sc + bv;
      }
    }
  }
}

extern "C" void kernel_launch(void* const* d_in, const int* in_sizes, int n_in,
                              void* d_out, int out_size, void* d_ws, size_t ws_size,
                              hipStream_t stream) {
  const float* inp = (const float*)d_in[0];
  const float* weight = (const float*)d_in[1];
  const float* bias = (const float*)d_in[2];
  float* out = (float*)d_out;

  const int N = in_sizes[2];                 // 16384
  const int K = in_sizes[1] / N;             // 4096
  const int M = in_sizes[0] / K;             // 8192

  uint8_t* ws = (uint8_t*)d_ws;
  unsigned int* amax = (unsigned int*)ws;
  uint8_t* xq = ws + 256;
  uint8_t* wqt = ws + 256 + (size_t)M * K;

  // log2(K/16) on host (K = 4096 -> ks16 = 8)
  int ks16 = 0;
  while ((1 << (ks16 + 4)) < K) ++ks16;

  hipMemsetAsync(d_ws, 0, 8, stream);  // zero the two atomic absmax slots

  absmax_both_kernel<<<2048, 256, 0, stream>>>(
      (const float4*)weight, (size_t)K * N / 4,
      (const float4*)inp, (size_t)M * K / 4, amax);

  quantize_x_kernel<<<4096, 256, 0, stream>>>((const float4*)inp, xq, amax,
                                              K, ks16, M * K / 16);
  quantize_wT_kernel<<<dim3(N / 64, K / 128), 256, 0, stream>>>(weight, wqt,
                                                                amax, N, K);

  gemm_fp8_mx<<<(M / T_BM) * (N / T_BN), 1024, 131072, stream>>>(
      xq, wqt, bias, amax, out, M, N, K);
}

// Round 16
// 861.274 us; speedup vs baseline: 1.1539x; 1.1539x over previous
//
#include <hip/hip_runtime.h>
#include <stdint.h>
#include <stddef.h>

typedef float f32x16 __attribute__((ext_vector_type(16)));
typedef int i32x8 __attribute__((ext_vector_type(8)));

union Frag32 { long l[4]; i32x8 v; };  // 32 bytes = one scaled-MFMA operand/lane

// ---------------------------------------------------------------------------
// CHAMPION (R12 revert — best measured configuration: 861 us total).
//
// Quantized operands live in an "LDS-image" layout: 8 KB slots; slot
// s = blk*(K/32) + ksl holds rows [blk*256..+256) x k-bytes [ksl*32..+32),
// logical L = row*32 + kkb stored at physical P = L ^ (((L>>7)&3)<<3)
// (8B-chunk 2-bit XOR; b64 fragment pattern P = h*8192 + row*32 +
// ((j ^ ((row>>2)&3))*8) is bank-pair bijective per 16-lane quarter:
// SQ_LDS_BANK_CONFLICT == 0, verified R3-R6/R11/R12/R14).
//
// GEMM: 256x256 tile, 16 waves of 64x64, 32x32x64 MX MFMA (unit E8M0
// scales -> bit-exact fp8 at the 2x MX rate), 4-slice LDS ring, lead-2
// gl_lds staging, counted vmcnt(2) (never 0 in loop), one barrier/phase,
// 2D-chunked XCD swizzle. Measured: 571 us, MfmaUtil 45, conflicts 0.
// Ledger: 256 ds_read_b64 x 8cy + staging ~= 2350 cy vs 2686 cy/phase
// measured -> ~87% LDS-unit-bound. Falsified alternatives: b128 (XOR'd
// R8 +4cy tax; lane-linear R15 slower return), VMEM-direct A/B (R9/R13
// latency exposure), 2-block split (R10), barrier halving (R8), L2
// topology (R11), coop prep fusion (R14). This is the structure's ceiling.
//
// Workspace: [0..7] amax slots | [256..) x_q 32MB | [+M*K..) w_qT 64MB.
// ---------------------------------------------------------------------------

__device__ __forceinline__ float max4(const float4 v) {
  return fmaxf(fmaxf(fabsf(v.x), fabsf(v.y)), fmaxf(fabsf(v.z), fabsf(v.w)));
}

// One kernel, both tensors: grid-stride scan of weight then inp, 4-way ILP.
__global__ void absmax_both_kernel(const float4* __restrict__ w, size_t wn4,
                                   const float4* __restrict__ x, size_t xn4,
                                   unsigned int* __restrict__ out) {
  const size_t tid0 = (size_t)blockIdx.x * blockDim.x + threadIdx.x;
  const size_t stride = (size_t)gridDim.x * blockDim.x * 4;
  float mw = 0.f, mx = 0.f;
  for (size_t i = tid0 * 4; i < wn4; i += stride) {
    float a = max4(w[i]), b = max4(w[i + 1]);
    float c = max4(w[i + 2]), d = max4(w[i + 3]);   // wn4 % 4 == 0
    mw = fmaxf(mw, fmaxf(fmaxf(a, b), fmaxf(c, d)));
  }
  for (size_t i = tid0 * 4; i < xn4; i += stride) {
    float a = max4(x[i]), b = max4(x[i + 1]);
    float c = max4(x[i + 2]), d = max4(x[i + 3]);   // xn4 % 4 == 0
    mx = fmaxf(mx, fmaxf(fmaxf(a, b), fmaxf(c, d)));
  }
#pragma unroll
  for (int off = 32; off > 0; off >>= 1) {
    mw = fmaxf(mw, __shfl_xor(mw, off));
    mx = fmaxf(mx, __shfl_xor(mx, off));
  }
  if ((threadIdx.x & 63) == 0) {
    atomicMax(out + 0, __float_as_uint(mw));  // vals >= 0: uint order == float
    atomicMax(out + 1, __float_as_uint(mx));
  }
}

// x [M][K] f32 -> LDS-image slots (8B-chunk swizzle: two 8B stores).
// ksh = log2(K/32): all index math is shifts/masks (no integer division).
__global__ void quantize_x_kernel(const float4* __restrict__ x,
                                  uint8_t* __restrict__ xq,
                                  const unsigned int* __restrict__ amax,
                                  int K, int ksh, int n_chunks) {
  const float x_scale = __uint_as_float(amax[1]) / 448.0f;
  const float inv = 1.0f / x_scale;
  int idx = blockIdx.x * blockDim.x + threadIdx.x;
  const int stride = gridDim.x * blockDim.x;
  for (; idx < n_chunks; idx += stride) {
    const int slot = idx >> 9;        // 512 chunks of 16B per 8KB slot
    const int p16 = idx & 511;
    const int row = p16 >> 1;
    const int kkb0 = (p16 & 1) << 4;
    const int mblk = slot >> ksh;
    const int ksl = slot & ((1 << ksh) - 1);
    const size_t f4 = ((size_t)(mblk * 256 + row) * K + ksl * 32 + kkb0) >> 2;
    const float4 v0 = x[f4 + 0], v1 = x[f4 + 1], v2 = x[f4 + 2], v3 = x[f4 + 3];
    uint32_t c0 = __builtin_amdgcn_cvt_pk_fp8_f32(v0.x * inv, v0.y * inv, 0, false);
    c0 = __builtin_amdgcn_cvt_pk_fp8_f32(v0.z * inv, v0.w * inv, c0, true);
    uint32_t c1 = __builtin_amdgcn_cvt_pk_fp8_f32(v1.x * inv, v1.y * inv, 0, false);
    c1 = __builtin_amdgcn_cvt_pk_fp8_f32(v1.z * inv, v1.w * inv, c1, true);
    uint32_t c2 = __builtin_amdgcn_cvt_pk_fp8_f32(v2.x * inv, v2.y * inv, 0, false);
    c2 = __builtin_amdgcn_cvt_pk_fp8_f32(v2.z * inv, v2.w * inv, c2, true);
    uint32_t c3 = __builtin_amdgcn_cvt_pk_fp8_f32(v3.x * inv, v3.y * inv, 0, false);
    c3 = __builtin_amdgcn_cvt_pk_fp8_f32(v3.z * inv, v3.w * inv, c3, true);
    const unsigned long long L0 = (unsigned long long)c0 | ((unsigned long long)c1 << 32);
    const unsigned long long L1 = (unsigned long long)c2 | ((unsigned long long)c3 << 32);
    const int Lc = row * 32 + kkb0;
    const int mask = ((row >> 2) & 3) << 3;
    const int addr0 = Lc ^ (mask & 16);
    uint8_t* p = xq + (size_t)slot * 8192;
    *(unsigned long long*)(p + addr0 + (mask & 8)) = L0;
    *(unsigned long long*)(p + addr0 + (8 ^ (mask & 8))) = L1;
  }
}

// w [K][N] f32 -> w^T LDS-image slots. 64n x 128k tile per block:
// f32 LDS tile [64][129] (conflict-free writes + b128 column reads),
// register-side 8B-chunk permute, two contiguous 16B stores.
__global__ void quantize_wT_kernel(const float* __restrict__ w,
                                   uint8_t* __restrict__ wqt,
                                   const unsigned int* __restrict__ amax,
                                   int N, int K) {
  __shared__ float tileF[64][129];
  const float w_scale = __uint_as_float(amax[0]) / 448.0f;
  const float inv = 1.0f / w_scale;
  const int tn = blockIdx.x;   // 64-wide n tile
  const int tk = blockIdx.y;   // 128-wide k tile
  const int t = threadIdx.x;
  {
    const int nn4 = t & 15;
    const int kk0 = t >> 4;    // 0..15
#pragma unroll
    for (int i = 0; i < 8; ++i) {
      const int kk = kk0 + i * 16;  // 0..127
      const float4 v =
          *(const float4*)&w[(size_t)(tk * 128 + kk) * N + tn * 64 + nn4 * 4];
      tileF[nn4 * 4 + 0][kk] = v.x;
      tileF[nn4 * 4 + 1][kk] = v.y;
      tileF[nn4 * 4 + 2][kk] = v.z;
      tileF[nn4 * 4 + 3][kk] = v.w;
    }
  }
  __syncthreads();
  {
    const int n = t & 63;
    const int c = t >> 6;      // 0..3: which 32-k chunk (wave-uniform)
    unsigned long long q[4];
#pragma unroll
    for (int cc = 0; cc < 4; ++cc) {
      const float4 u0 = *(const float4*)&tileF[n][c * 32 + cc * 8];
      const float4 u1 = *(const float4*)&tileF[n][c * 32 + cc * 8 + 4];
      uint32_t lo = __builtin_amdgcn_cvt_pk_fp8_f32(u0.x * inv, u0.y * inv, 0, false);
      lo = __builtin_amdgcn_cvt_pk_fp8_f32(u0.z * inv, u0.w * inv, lo, true);
      uint32_t hi = __builtin_amdgcn_cvt_pk_fp8_f32(u1.x * inv, u1.y * inv, 0, false);
      hi = __builtin_amdgcn_cvt_pk_fp8_f32(u1.z * inv, u1.w * inv, hi, true);
      q[cc] = (unsigned long long)lo | ((unsigned long long)hi << 32);
    }
    const int n_g = tn * 64 + n;
    const int k0g = tk * 128 + c * 32;
    const size_t slot = (size_t)(n_g >> 8) * (K >> 5) + (k0g >> 5);
    const int row = n_g & 255;
    const int m2 = (row >> 2) & 3;    // physical chunk p holds logical p^m2
    ulonglong2 s0, s1;
    s0.x = q[0 ^ m2]; s0.y = q[1 ^ m2];
    s1.x = q[2 ^ m2]; s1.y = q[3 ^ m2];
    uint8_t* pbase = wqt + slot * 8192 + row * 32;
    *(ulonglong2*)(pbase) = s0;
    *(ulonglong2*)(pbase + 16) = s1;
  }
}

// ---------------------------------------------------------------------------
// fp8 GEMM (champion structure).
// ---------------------------------------------------------------------------
#define T_BM 256
#define T_BN 256
#define UNIT_SCALE 0x7F7F7F7F

__device__ __forceinline__ void gl_lds16(const uint8_t* g, uint8_t* lds) {
  __builtin_amdgcn_global_load_lds(
      (const __attribute__((address_space(1))) void*)g,
      (__attribute__((address_space(3))) void*)lds, 16, 0, 0);
}

__global__ __launch_bounds__(1024, 4) void gemm_fp8_mx(
    const uint8_t* __restrict__ Aq, const uint8_t* __restrict__ BqT,
    const float* __restrict__ bias, const unsigned int* __restrict__ amax,
    float* __restrict__ C, int M, int N, int K) {
  extern __shared__ uint8_t smem[];
  uint8_t* const Ar = smem;            // 4 slices x 16384 = 64 KB
  uint8_t* const Br = smem + 65536;    // 4 slices x 16384 = 64 KB

  // 2D-chunked XCD swizzle: co-resident 32 blocks per XCD = 4(tm) x 8(tn).
  const int ntm = M / T_BM;            // 32
  const int mpx = ntm >> 3;            // 4 m-tiles per XCD
  const int bid = blockIdx.x;
  const int s = bid >> 3;
  const int tm = (bid & 7) * mpx + (s & (mpx - 1));
  const int tn = s / mpx;
  const int m0 = tm * T_BM;
  const int n0 = tn * T_BN;

  const int tid = threadIdx.x;
  const int w = tid >> 6;      // wave 0..15
  const int l = tid & 63;
  const int wr = w >> 2;       // 0..3  (M quarter)
  const int wc = w & 3;        // 0..3  (N quarter)

  const int kslots = K >> 5;

  // staging: linear contiguous copy of one 16 KB slice; wave w owns bytes
  // [w*1024, w*1024+1024), lane l the 16B at +l*16.
  const int soff = w * 1024 + l * 16;
  const uint8_t* a_src = Aq + (size_t)(m0 >> 8) * kslots * 8192 + soff;
  const uint8_t* b_src = BqT + (size_t)(n0 >> 8) * kslots * 8192 + soff;

  // fragment-read offsets: lane half h = l>>5 -> slot h within the slice.
  const int h = l >> 5;
  const int rl = l & 31;
  int aoff[2][4], boff[2][4];
#pragma unroll
  for (int mt = 0; mt < 2; ++mt) {
    const int ra = wr * 64 + mt * 32 + rl;
    const int rb = wc * 64 + mt * 32 + rl;
#pragma unroll
    for (int j = 0; j < 4; ++j) {
      aoff[mt][j] = h * 8192 + ra * 32 + ((j ^ ((ra >> 2) & 3)) * 8);
      boff[mt][j] = h * 8192 + rb * 32 + ((j ^ ((rb >> 2) & 3)) * 8);
    }
  }

  f32x16 acc[2][2];
#pragma unroll
  for (int i = 0; i < 2; ++i)
#pragma unroll
    for (int j = 0; j < 2; ++j) acc[i][j] = 0.f;

  const int NP = K >> 6;  // 64 phases (one 16 KB slice each)

  // prologue: stage slices 0,1 into ring slots 0,1
  gl_lds16(a_src, Ar + soff);
  gl_lds16(b_src, Br + soff);
  gl_lds16(a_src + 16384, Ar + 16384 + soff);
  gl_lds16(b_src + 16384, Br + 16384 + soff);
  asm volatile("s_waitcnt vmcnt(2)" ::: "memory");  // slice 0 landed
  __builtin_amdgcn_s_barrier();

  for (int p = 0; p < NP; ++p) {
    // 1. stage slice p+2 (tail: re-stage p-2 = same bytes into its dead slot)
    const int ss = (p + 2 < NP) ? (p + 2) : (p - 2);
    const int rslot = ((p + 2) & 3) * 16384;
    gl_lds16(a_src + (size_t)ss * 16384, Ar + rslot + soff);
    gl_lds16(b_src + (size_t)ss * 16384, Br + rslot + soff);

    // 2. fragments from ring slot p&3 (compiler-managed lgkmcnt)
    const uint8_t* Asl = Ar + (p & 3) * 16384;
    const uint8_t* Bsl = Br + (p & 3) * 16384;
    Frag32 af[2], bf[2];
#pragma unroll
    for (int t2 = 0; t2 < 2; ++t2)
#pragma unroll
      for (int j = 0; j < 4; ++j) {
        af[t2].l[j] = *(const long*)(Asl + aoff[t2][j]);
        bf[t2].l[j] = *(const long*)(Bsl + boff[t2][j]);
      }

    // 3. 4 MFMAs (64x64 per wave)
    __builtin_amdgcn_s_setprio(1);
    acc[0][0] = __builtin_amdgcn_mfma_scale_f32_32x32x64_f8f6f4(
        af[0].v, bf[0].v, acc[0][0], 0, 0, 0, UNIT_SCALE, 0, UNIT_SCALE);
    acc[1][0] = __builtin_amdgcn_mfma_scale_f32_32x32x64_f8f6f4(
        af[1].v, bf[0].v, acc[1][0], 0, 0, 0, UNIT_SCALE, 0, UNIT_SCALE);
    acc[0][1] = __builtin_amdgcn_mfma_scale_f32_32x32x64_f8f6f4(
        af[0].v, bf[1].v, acc[0][1], 0, 0, 0, UNIT_SCALE, 0, UNIT_SCALE);
    acc[1][1] = __builtin_amdgcn_mfma_scale_f32_32x32x64_f8f6f4(
        af[1].v, bf[1].v, acc[1][1], 0, 0, 0, UNIT_SCALE, 0, UNIT_SCALE);
    __builtin_amdgcn_s_setprio(0);

    // 4. counted wait: slice p+1 must land; slice p+2's pair stays in flight
    asm volatile("s_waitcnt vmcnt(2)" ::: "memory");
    __builtin_amdgcn_s_barrier();
  }
  asm volatile("s_waitcnt vmcnt(0)" ::: "memory");  // drain tail dummies

  // epilogue: C = acc * (x_scale*w_scale) + bias
  // 32x32 C/D layout: col = l&31, row = (r&3) + 8*(r>>2) + 4*(l>>5)
  const float x_scale = __uint_as_float(amax[1]) / 448.0f;
  const float w_scale = __uint_as_float(amax[0]) / 448.0f;
  const float sc = x_scale * w_scale;
  const int colb = n0 + wc * 64 + rl;
  const int rowb = m0 + wr * 64 + 4 * h;
#pragma unroll
  for (int nt = 0; nt < 2; ++nt) {
    const int col = colb + nt * 32;
    const float bv = bias[col];
#pragma unroll
    for (int mt = 0; mt < 2; ++mt) {
#pragma unroll
      for (int r = 0; r < 16; ++r) {
        const int row = rowb + mt * 32 + (r & 3) + 8 * (r >> 2);
        C[(size_t)row * N + col] = acc[mt][nt][r] * sc + bv;
      }
    }
  }
}

extern "C" void kernel_launch(void* const* d_in, const int* in_sizes, int n_in,
                              void* d_out, int out_size, void* d_ws, size_t ws_size,
                              hipStream_t stream) {
  const float* inp = (const float*)d_in[0];
  const float* weight = (const float*)d_in[1];
  const float* bias = (const float*)d_in[2];
  float* out = (float*)d_out;

  const int N = in_sizes[2];                 // 16384
  const int K = in_sizes[1] / N;             // 4096
  const int M = in_sizes[0] / K;             // 8192

  uint8_t* ws = (uint8_t*)d_ws;
  unsigned int* amax = (unsigned int*)ws;
  uint8_t* xq = ws + 256;
  uint8_t* wqt = ws + 256 + (size_t)M * K;

  // log2(K/32) on host (K is a power of two here: 4096 -> ksh = 7)
  int ksh = 0;
  while ((1 << (ksh + 5)) < K) ++ksh;

  hipMemsetAsync(d_ws, 0, 8, stream);  // zero the two atomic absmax slots

  absmax_both_kernel<<<2048, 256, 0, stream>>>(
      (const float4*)weight, (size_t)K * N / 4,
      (const float4*)inp, (size_t)M * K / 4, amax);

  quantize_x_kernel<<<4096, 256, 0, stream>>>((const float4*)inp, xq, amax,
                                              K, ksh, M * K / 16);
  quantize_wT_kernel<<<dim3(N / 64, K / 128), 256, 0, stream>>>(weight, wqt,
                                                                amax, N, K);

  gemm_fp8_mx<<<(M / T_BM) * (N / T_BN), 1024, 131072, stream>>>(
      xq, wqt, bias, amax, out, M, N, K);
}